// Round 3
// baseline (151.449 us; speedup 1.0000x reference)
//
#include <hip/hip_runtime.h>

#define M_TOT 32768
#define K_TOT 768
#define N_TOT 768

typedef int v4i __attribute__((ext_vector_type(4)));
typedef unsigned int v4u __attribute__((ext_vector_type(4)));

#define GLOAD_LDS(g, l) __builtin_amdgcn_global_load_lds( \
    (const __attribute__((address_space(1))) unsigned int*)(g), \
    (__attribute__((address_space(3))) unsigned int*)(l), 16, 0, 0)

// Pack 4 int32 (each holding an int8 value) into one dword of 4 bytes.
__device__ __forceinline__ unsigned pack4(v4i a) {
  unsigned lo = __builtin_amdgcn_perm((unsigned)a.y, (unsigned)a.x, 0x00000400u);
  unsigned hi = __builtin_amdgcn_perm((unsigned)a.w, (unsigned)a.z, 0x00000400u);
  return __builtin_amdgcn_perm(hi, lo, 0x05040100u);
}

// W[k][n] int32 -> W8T[n][k] int8 (transposed, packed)
__global__ __launch_bounds__(256) void pack_w_kernel(const int* __restrict__ W,
                                                     signed char* __restrict__ W8T) {
  __shared__ signed char t[64][72];
  const int k0 = blockIdx.x * 64, n0 = blockIdx.y * 64;
  for (int i = threadIdx.x; i < 4096; i += 256) {
    int k = i >> 6, n = i & 63;
    t[n][k] = (signed char)W[(k0 + k) * N_TOT + n0 + n];
  }
  __syncthreads();
  for (int i = threadIdx.x; i < 4096; i += 256) {
    int n = i >> 6, k = i & 63;
    W8T[(n0 + n) * K_TOT + k0 + k] = t[n][k];
  }
}

// out_i32 = clamp(round((X@W)*alpha + bias))
// X: int32-holding-int8 [M][K]; W8T: int8 [N][K]; out: int32 [M][N].
// Structure: whole W-slice (128 cols x 768 k = 96KB) staged in LDS ONCE;
// A fragments loaded global->register per K-step; ZERO barriers in K-loop.
// Block 512 thr = 8 waves (4Mx2N), tile 256x128, wave 64x64 via 4x4 mfma.
__global__ __launch_bounds__(512, 2) void gemm_i8_kernel(
    const int* __restrict__ X, const signed char* __restrict__ W8T,
    const float* __restrict__ bias, const float* __restrict__ alpha_p,
    int* __restrict__ out) {
  __shared__ signed char Bl[128 * K_TOT];  // 96 KB

  // Bijective XCD-chunked swizzle: 768 wgs = 8 XCDs x 96; nt fast within chunk
  // so the 6 sibling N-tiles of one X M-panel run ~concurrently on one XCD/L2.
  const int d = blockIdx.x;
  const int t = (d & 7) * 96 + (d >> 3);
  const int mt = t / 6, nt = t - mt * 6;
  const int row0 = mt << 8, col0 = nt << 7;

  const int tid = threadIdx.x;
  const int lane = tid & 63;
  const int wave = tid >> 6;              // 0..7
  const int wr = wave >> 1, wc = wave & 1;
  const int fr = lane & 15, fg = lane >> 4;
  const int frsw = (fr & 7) << 4;         // B-read XOR swizzle

  // ---- A prologue loads (issue first: HBM/L2 latency) ----
  // Wave wr covers rows row0 + wr*64 + m*16 + fr; lane holds k-bytes fg*16..+16
  const int* Xw = X + (row0 + wr * 64 + fr) * K_TOT + fg * 16;
  v4i q[4][4];
#pragma unroll
  for (int m = 0; m < 4; ++m)
#pragma unroll
    for (int j = 0; j < 4; ++j)
      q[m][j] = *(const v4i*)(Xw + m * 16 * K_TOT + j * 4);

  // ---- Stage whole W-slice into LDS (once), XOR-swizzled ----
  // LDS[n*768 + p] = W8T[col0+n][p ^ ((n&7)<<4)]  (16B-chunk granularity)
#pragma unroll
  for (int i = 0; i < 12; ++i) {
    int c = i * 512 + tid;               // 16B-chunk index, 6144 total
    int n = c / 48;                      // 48 chunks per n-row
    int rem = c - n * 48;
    int src = (col0 + n) * K_TOT + ((rem * 16) ^ ((n & 7) << 4));
    GLOAD_LDS(W8T + src, &Bl[i * 8192 + wave * 1024]);
  }

  const v4i zero = {0, 0, 0, 0};
  v4i acc[4][4];
#pragma unroll
  for (int m = 0; m < 4; ++m)
#pragma unroll
    for (int n = 0; n < 4; ++n) acc[m][n] = zero;

  __syncthreads();  // W-slice ready (drains gload_lds + prologue q)

  // B-frag LDS row bases (rn & 7 == fr & 7, so swizzle is uniform over n)
  int brow[4];
#pragma unroll
  for (int n = 0; n < 4; ++n) brow[n] = (wc * 64 + n * 16 + fr) * K_TOT;

  // ---- K-loop: NO barriers. pack q -> af; issue next q; ds_read bf; mfma ----
#pragma unroll
  for (int ks = 0; ks < 12; ++ks) {
    v4i af[4];
#pragma unroll
    for (int m = 0; m < 4; ++m) {
      v4i a;
      a.x = (int)pack4(q[m][0]);
      a.y = (int)pack4(q[m][1]);
      a.z = (int)pack4(q[m][2]);
      a.w = (int)pack4(q[m][3]);
      af[m] = a;
    }

    if (ks + 1 < 12) {  // T14: issue next-step loads early; consumed next iter
#pragma unroll
      for (int m = 0; m < 4; ++m)
#pragma unroll
        for (int j = 0; j < 4; ++j)
          q[m][j] = *(const v4i*)(Xw + (ks + 1) * 64 + m * 16 * K_TOT + j * 4);
    }

    v4i bf[4];
    const int ka = (ks * 64 + fg * 16) ^ frsw;
#pragma unroll
    for (int n = 0; n < 4; ++n)
      bf[n] = *(const v4i*)&Bl[brow[n] + ka];

#pragma unroll
    for (int m = 0; m < 4; ++m)
#pragma unroll
      for (int n = 0; n < 4; ++n)
        acc[m][n] = __builtin_amdgcn_mfma_i32_16x16x64_i8(af[m], bf[n], acc[m][n], 0, 0, 0);
  }

  // ---- Epilogue: C/D layout col = lane&15, row = (lane>>4)*4 + reg ----
  const float alpha = *alpha_p;
  float bv[4];
#pragma unroll
  for (int n = 0; n < 4; ++n) bv[n] = bias[col0 + wc * 64 + n * 16 + fr];

#pragma unroll
  for (int m = 0; m < 4; ++m) {
    int orow = row0 + wr * 64 + m * 16 + fg * 4;
#pragma unroll
    for (int n = 0; n < 4; ++n) {
      int ocol = col0 + wc * 64 + n * 16 + fr;
      int* po = out + orow * N_TOT + ocol;
#pragma unroll
      for (int r = 0; r < 4; ++r) {
        float v = rintf((float)acc[m][n][r] * alpha + bv[n]);
        v = fminf(127.f, fmaxf(-128.f, v));
        po[r * N_TOT] = (int)v;
      }
    }
  }
}

extern "C" void kernel_launch(void* const* d_in, const int* in_sizes, int n_in,
                              void* d_out, int out_size, void* d_ws, size_t ws_size,
                              hipStream_t stream) {
  const int* X = (const int*)d_in[0];        // [4,8192,768] int8 promoted to int32
  const int* W = (const int*)d_in[1];        // [768,768] int8 promoted to int32
  const float* bias = (const float*)d_in[2]; // [1,768] fp16 promoted to float32
  const float* alpha = (const float*)d_in[3];
  int* out = (int*)d_out;                    // int8 output promoted to int32
  signed char* W8T = (signed char*)d_ws;     // 768*768 = 589,824 B scratch

  dim3 pg(K_TOT / 64, N_TOT / 64);
  pack_w_kernel<<<pg, 256, 0, stream>>>(W, W8T);
  gemm_i8_kernel<<<(M_TOT / 256) * (N_TOT / 128), 512, 0, stream>>>(X, W8T, bias, alpha, out);
}

// Round 4
// 55.040 us; speedup vs baseline: 2.7516x; 2.7516x over previous
//
#include <hip/hip_runtime.h>

#define M_TOT 32768
#define K_TOT 768
#define N_TOT 768

typedef int v4i __attribute__((ext_vector_type(4)));

#define GLOAD_LDS(g, l) __builtin_amdgcn_global_load_lds( \
    (const __attribute__((address_space(1))) unsigned int*)(g), \
    (__attribute__((address_space(3))) unsigned int*)(l), 16, 0, 0)

// Pack 4 int32 (each holding an int8 value) into one dword of 4 bytes. (verified R2)
__device__ __forceinline__ unsigned pack4(v4i a) {
  unsigned lo = __builtin_amdgcn_perm((unsigned)a.y, (unsigned)a.x, 0x00000400u);
  unsigned hi = __builtin_amdgcn_perm((unsigned)a.w, (unsigned)a.z, 0x00000400u);
  return __builtin_amdgcn_perm(hi, lo, 0x05040100u);
}

// W[k][n] int32 -> W8T[n][k] int8 (transposed, packed)
__global__ __launch_bounds__(256) void pack_w_kernel(const int* __restrict__ W,
                                                     signed char* __restrict__ W8T) {
  __shared__ signed char t[64][72];
  const int k0 = blockIdx.x * 64, n0 = blockIdx.y * 64;
  for (int i = threadIdx.x; i < 4096; i += 256) {
    int k = i >> 6, n = i & 63;
    t[n][k] = (signed char)W[(k0 + k) * N_TOT + n0 + n];
  }
  __syncthreads();
  for (int i = threadIdx.x; i < 4096; i += 256) {
    int n = i >> 6, k = i & 63;
    W8T[(n0 + n) * K_TOT + k0 + k] = t[n][k];
  }
}

// out_i32 = clamp(round((X@W)*alpha + bias))
// Depth-2 counted-vmcnt pipeline (T3/T4): per K-step, issue A-loads(t+2) +
// B-gloads(t+2); ONE raw s_barrier per iter; vmcnt never drained to 0 in
// steady state. Per-thread vmem per stage: 8 A global_load_dwordx4 + 2
// B global_load_lds (in-order retirement => exact counting).
// Buffers: A 2-ring (reg->pack->ds_write), B 3-ring (gload_lds direct).
__global__ __launch_bounds__(256, 2) void gemm_i8_kernel(
    const int* __restrict__ X, const signed char* __restrict__ W8T,
    const float* __restrict__ bias, const float* __restrict__ alpha_p,
    int* __restrict__ out) {
  __shared__ __align__(16) signed char Abuf[2][8192];
  __shared__ __align__(16) signed char Bbuf[3][8192];

  // Bijective XCD-chunked swizzle: 1536 wgs = 8 XCDs x 192; nt fast so the 6
  // sibling N-tiles of one X M-panel share that XCD's L2.
  const int d = blockIdx.x;
  const int t = (d & 7) * 192 + (d >> 3);
  const int mt = t / 6, nt = t - mt * 6;
  const int row0 = mt << 7, col0 = nt << 7;

  const int tid = threadIdx.x;
  const int lane = tid & 63;
  const int wave = tid >> 6;
  const int wr = wave >> 1, wc = wave & 1;
  const int fr = lane & 15, fg = lane >> 4;
  const int fsw = (fr & 3) << 4;          // frag-read XOR swizzle

  // A loads: chunk j covers row rA = 16*j + (tid>>4), int-cols (tid&15)*4..+4
  // => each dwordx4 instr is a fully-coalesced 1KB wave access.
  const int arow = tid >> 4;              // 0..15
  const int acol = (tid & 15) << 2;       // int col within 64-int stage
  const int* Xbase = X + (row0 + arow) * K_TOT + acol;
  const int awsw = (arow & 3) << 4;       // (16j+arow)&3 == arow&3

  // B gloads: chunk c = i*256+tid: row rB=c>>2, slot s=(c&3)*16; source
  // pre-swizzled so linear LDS + swizzled read = consistent (rule #21).
  int bsrc[2], bdst[2];
#pragma unroll
  for (int i = 0; i < 2; ++i) {
    int c = i * 256 + tid;
    int r = c >> 2, s = (c & 3) << 4;
    bsrc[i] = (col0 + r) * K_TOT + (s ^ ((r & 3) << 4));
    bdst[i] = i * 4096 + wave * 1024;     // wave-uniform base; HW adds lane*16
  }

  v4i q[2][8];
  const v4i zero = {0, 0, 0, 0};
  v4i acc[4][4];
#pragma unroll
  for (int m = 0; m < 4; ++m)
#pragma unroll
    for (int n = 0; n < 4; ++n) acc[m][n] = zero;

#define ISSUE_A(ks)                                                      \
  do {                                                                   \
    const int* _p = Xbase + (ks) * 64;                                   \
    _Pragma("unroll") for (int j = 0; j < 8; ++j)                        \
        q[(ks) & 1][j] = *(const v4i*)(_p + j * 16 * K_TOT);             \
  } while (0)

#define ISSUE_B(ks)                                                      \
  do {                                                                   \
    const signed char* _w = W8T + (ks) * 64;                             \
    signed char* _lb = Bbuf[(ks) % 3];                                   \
    GLOAD_LDS(_w + bsrc[0], _lb + bdst[0]);                              \
    GLOAD_LDS(_w + bsrc[1], _lb + bdst[1]);                              \
  } while (0)

#define PACK_WRITE_A(tt)                                                 \
  do {                                                                   \
    signed char* _ab = Abuf[(tt) & 1];                                   \
    _Pragma("unroll") for (int j = 0; j < 8; ++j) {                      \
      unsigned _dw = pack4(q[(tt) & 1][j]);                              \
      *(unsigned*)&_ab[(16 * j + arow) * 64 + (acol ^ awsw)] = _dw;      \
    }                                                                    \
  } while (0)

#define FRAGS_MFMA(ks)                                                   \
  do {                                                                   \
    v4i af[4], bf[4];                                                    \
    const signed char* _ab = Abuf[(ks) & 1];                             \
    const signed char* _bb = Bbuf[(ks) % 3];                             \
    const int _kb = (fg << 4) ^ fsw;                                     \
    _Pragma("unroll") for (int m = 0; m < 4; ++m)                        \
        af[m] = *(const v4i*)&_ab[(wr * 64 + m * 16 + fr) * 64 + _kb];   \
    _Pragma("unroll") for (int n = 0; n < 4; ++n)                        \
        bf[n] = *(const v4i*)&_bb[(wc * 64 + n * 16 + fr) * 64 + _kb];   \
    _Pragma("unroll") for (int m = 0; m < 4; ++m)                        \
        _Pragma("unroll") for (int n = 0; n < 4; ++n)                    \
            acc[m][n] = __builtin_amdgcn_mfma_i32_16x16x64_i8(           \
                af[m], bf[n], acc[m][n], 0, 0, 0);                       \
  } while (0)

  // GITER: top-wait (B(ks) + cross-wave A ds_writes) -> barrier -> issue
  // stage ks+2 -> frags+MFMA(ks) -> mid-wait (A(ks+1) regs) -> pack+write.
#define GITER(ks, TOPW, MIDW)                                            \
  do {                                                                   \
    asm volatile("s_waitcnt vmcnt(" TOPW ") lgkmcnt(0)" ::: "memory");   \
    __builtin_amdgcn_s_barrier();                                        \
    if ((ks) + 2 < 12) { ISSUE_A((ks) + 2); ISSUE_B((ks) + 2); }         \
    FRAGS_MFMA(ks);                                                      \
    if ((ks) + 1 < 12) {                                                 \
      asm volatile("s_waitcnt vmcnt(" MIDW ")" ::: "memory");            \
      PACK_WRITE_A((ks) + 1);                                            \
    }                                                                    \
  } while (0)

  // Prologue: stages 0 and 1 in flight; pack A(0).
  ISSUE_A(0); ISSUE_B(0);
  ISSUE_A(1); ISSUE_B(1);
  asm volatile("s_waitcnt vmcnt(12)" ::: "memory");  // A(0) retired
  PACK_WRITE_A(0);

  // vmcnt ledger (10 vmem/stage): steady top=10 (leaves A(k+1),B(k+1)),
  // mid=12 (leaves B(k+1),A(k+2),B(k+2)). Boundaries: ks=10 mid=2, ks=11 top=0.
  GITER(0, "10", "12");
  GITER(1, "10", "12");
  GITER(2, "10", "12");
  GITER(3, "10", "12");
  GITER(4, "10", "12");
  GITER(5, "10", "12");
  GITER(6, "10", "12");
  GITER(7, "10", "12");
  GITER(8, "10", "12");
  GITER(9, "10", "12");
  GITER(10, "10", "2");
  GITER(11, "0", "0");

  // Epilogue: C/D layout col = lane&15, row = (lane>>4)*4 + reg. Output int32.
  const float alpha = *alpha_p;
  float bv[4];
#pragma unroll
  for (int n = 0; n < 4; ++n) bv[n] = bias[col0 + wc * 64 + n * 16 + fr];

#pragma unroll
  for (int m = 0; m < 4; ++m) {
    int orow = row0 + wr * 64 + m * 16 + fg * 4;
#pragma unroll
    for (int n = 0; n < 4; ++n) {
      int ocol = col0 + wc * 64 + n * 16 + fr;
      int* po = out + orow * N_TOT + ocol;
#pragma unroll
      for (int r = 0; r < 4; ++r) {
        float v = rintf((float)acc[m][n][r] * alpha + bv[n]);
        v = fminf(127.f, fmaxf(-128.f, v));
        po[r * N_TOT] = (int)v;
      }
    }
  }
}

extern "C" void kernel_launch(void* const* d_in, const int* in_sizes, int n_in,
                              void* d_out, int out_size, void* d_ws, size_t ws_size,
                              hipStream_t stream) {
  const int* X = (const int*)d_in[0];        // [4,8192,768] int8 promoted to int32
  const int* W = (const int*)d_in[1];        // [768,768] int8 promoted to int32
  const float* bias = (const float*)d_in[2]; // [1,768] fp16 promoted to float32
  const float* alpha = (const float*)d_in[3];
  int* out = (int*)d_out;                    // int8 output promoted to int32
  signed char* W8T = (signed char*)d_ws;     // 768*768 = 589,824 B scratch

  dim3 pg(K_TOT / 64, N_TOT / 64);
  pack_w_kernel<<<pg, 256, 0, stream>>>(W, W8T);
  gemm_i8_kernel<<<(M_TOT / 128) * (N_TOT / 128), 256, 0, stream>>>(X, W8T, bias, alpha, out);
}